// Round 4
// baseline (306.684 us; speedup 1.0000x reference)
//
#include <hip/hip_runtime.h>
#include <stdint.h>

#define THREADS 64          // block == one wave: simplest global_load_lds case
#define ROWPAD  84          // LDS dwords per sample row: 3 x [27 data + 1 pad]
#define TILE_DW (64 * 81)   // 5184 global dwords staged per wave

typedef const __attribute__((address_space(1))) uint32_t* gas_ptr;
typedef __attribute__((address_space(3))) uint32_t*       las_ptr;

__device__ __forceinline__ float fast_sigmoid(float v) {
    float e = __expf(-v);
    return __builtin_amdgcn_rcpf(1.0f + e);
}

// Round-3 diagnosis: per-lane 324B stride makes every load instr a 64-line
// gather; 662KB/CU live footprint vs 32KB L1 -> each 128B line re-fetched ~8x
// from L2/L3 (~1.4GB secondary traffic for a 170MB input). Explains warm==cold
// ~100us (L3-BW-bound) with clean FETCH_SIZE. Fix: stage each wave's 64
// samples into LDS with fully-coalesced global_load_lds (lines consumed once),
// then per-thread ds_read_b128 from a group-padded layout.
__global__ __launch_bounds__(THREADS, 2) void olcnn_kernel(
    const float* __restrict__ x,
    const float* __restrict__ Wc, const float* __restrict__ bc,
    const float* __restrict__ Wh, const float* __restrict__ bh,
    const float* __restrict__ Wm, const float* __restrict__ bm,
    const float* __restrict__ Wo, const float* __restrict__ bo,
    float* __restrict__ out)
{
    // 64 rows x 84 dwords = 21504 B -> 7 blocks/CU; 145KB of loads in flight
    // per CU >> latency-BW product, so HBM saturates at low occupancy.
    __shared__ __align__(16) float sm[64 * ROWPAD];

    const int lane  = threadIdx.x;
    const int s     = blockIdx.x * THREADS + lane;
    const int Wd    = blockIdx.x * TILE_DW;          // dword base of this tile
    const int TOTAL = (int)gridDim.x * TILE_DW;      // B*81 dwords (42.5M, fits)

    // ---- stage: chunk c = i*64+lane; row t = c/21, r = c%21, grp = r/7 ----
    // LDS dest (implicit, linear) = dword c*4  ==  row t*84 + grp*28 + 4*(r-7g)
    // global src f0 = t*81 + 4r - grp  (grp*27 + 4*jj collapsed)
    {
        int t = (lane * 6242) >> 17;                 // lane / 21 (exact, c<13107)
        int r = lane - t * 21;
        #pragma unroll
        for (int i = 0; i < 21; ++i) {
            const int grp = (r * 19) >> 7;           // r / 7 (exact, r<26)
            int f0 = Wd + t * 81 + (r << 2) - grp;
            const int lim = TOTAL - 4;               // only global-final chunk clamps
            f0 = (f0 < lim) ? f0 : lim;
            __builtin_amdgcn_global_load_lds(
                (gas_ptr)(x + f0), (las_ptr)(&sm[i * 256]), 16, 0, 0);
            // c += 64  =>  r += 1 (wrap at 21 carries into t), t += 3
            t += 3 + (r == 20);
            r = (r == 20) ? 0 : r + 1;
        }
    }
    __syncthreads();    // drains vmcnt -> LDS visible (1-wave block: cheap)

    float res[4];

    #pragma unroll
    for (int G = 0; G < 3; ++G) {
        // This sample's group-G pixels: 28 dwords (27 real + 1 pad), 16B-aligned
        // (row*336B + G*112B). Stride-84 start banks = 8 distinct 4-bank sets,
        // 8 lanes each — same class as contiguous b128 (conflict-benign).
        float p[28];
        {
            const float4* rp = (const float4*)&sm[lane * ROWPAD + G * 28];
            #pragma unroll
            for (int q = 0; q < 7; ++q) {
                float4 v = rp[q];
                p[4*q+0] = v.x; p[4*q+1] = v.y; p[4*q+2] = v.z; p[4*q+3] = v.w;
            }
        }
        // Repair the one clamped chunk: last thread's group-2 tail shifted by 1.
        if (G == 2 && blockIdx.x == gridDim.x - 1 && lane == 63) {
            p[24] = x[TOTAL - 3]; p[25] = x[TOTAL - 2]; p[26] = x[TOTAL - 1];
        }

        float hbuf[9];
        #pragma unroll
        for (int j = 0; j < 3; ++j) {              // conv patch g = (G, j)
            const int g = G * 3 + j;
            float feat[9];
            #pragma unroll
            for (int k = 0; k < 9; ++k) {          // 9 independent chains -> ILP
                float acc = bc[g * 9 + k];
                #pragma unroll
                for (int pr = 0; pr < 3; ++pr)
                    #pragma unroll
                    for (int pc = 0; pc < 3; ++pc)
                        acc = fmaf(p[pr * 9 + j * 3 + pc],
                                   Wc[(g * 9 + k) * 9 + pr * 3 + pc], acc);
                feat[k] = fast_sigmoid(acc);
            }
            #pragma unroll
            for (int n = 0; n < 3; ++n) {
                float acc = bh[g * 3 + n];
                #pragma unroll
                for (int pidx = 0; pidx < 9; ++pidx)
                    acc = fmaf(feat[pidx], Wh[(g * 3 + n) * 9 + pidx], acc);
                hbuf[j * 3 + n] = fast_sigmoid(acc);
            }
        }

        float m[4];
        #pragma unroll
        for (int n = 0; n < 4; ++n) {
            float acc = bm[G * 4 + n];
            #pragma unroll
            for (int pidx = 0; pidx < 9; ++pidx)
                acc = fmaf(hbuf[pidx], Wm[(G * 4 + n) * 9 + pidx], acc);
            m[n] = fast_sigmoid(acc);
        }

        // outputs reading middle group G (c % 3 == G): c = G, plus c = 3 @ G = 0
        {
            float acc = bo[G];
            #pragma unroll
            for (int pidx = 0; pidx < 4; ++pidx)
                acc = fmaf(m[pidx], Wo[G * 4 + pidx], acc);
            res[G] = acc;
        }
        if (G == 0) {
            float acc = bo[3];
            #pragma unroll
            for (int pidx = 0; pidx < 4; ++pidx)
                acc = fmaf(m[pidx], Wo[3 * 4 + pidx], acc);
            res[3] = acc;
        }
    }

    float4 o;
    o.x = res[0]; o.y = res[1]; o.z = res[2]; o.w = res[3];
    ((float4*)out)[s] = o;                         // coalesced 16B/lane store
}

extern "C" void kernel_launch(void* const* d_in, const int* in_sizes, int n_in,
                              void* d_out, int out_size, void* d_ws, size_t ws_size,
                              hipStream_t stream) {
    const float* x  = (const float*)d_in[0];
    const float* Wc = (const float*)d_in[1];
    const float* bc = (const float*)d_in[2];
    const float* Wh = (const float*)d_in[3];
    const float* bh = (const float*)d_in[4];
    const float* Wm = (const float*)d_in[5];
    const float* bm = (const float*)d_in[6];
    const float* Wo = (const float*)d_in[7];
    const float* bo = (const float*)d_in[8];
    float* out = (float*)d_out;

    const int B = in_sizes[0] / 81;                // 524288
    const int blocks = B / THREADS;                // 8192 wave-tiles
    olcnn_kernel<<<blocks, THREADS, 0, stream>>>(x, Wc, bc, Wh, bh, Wm, bm,
                                                 Wo, bo, out);
}

// Round 5
// 298.382 us; speedup vs baseline: 1.0278x; 1.0278x over previous
//
#include <hip/hip_runtime.h>
#include <stdint.h>

#define THREADS 256
#define WAVE_DW 1792        // LDS dwords per wave: 64 samples x 28 dwords
#define GDW     28          // dwords per sample-group slot (27 data + 1 slack)

typedef const __attribute__((address_space(1))) uint32_t* gas_ptr;
typedef __attribute__((address_space(3))) uint32_t*       las_ptr;

__device__ __forceinline__ float fast_sigmoid(float v) {
    float e = __expf(-v);
    return __builtin_amdgcn_rcpf(1.0f + e);
}

// Round-4 post-mortem: full-sample LDS staging fixed the line-refetch
// amplification (FETCH 162->85MB, HBM 10% of peak) but 64-thread blocks +
// 21.5KB LDS left only 7 waves/CU (Occupancy 18%) and a serial
// stage->drain->compute chain per wave -> 127us, latency-bound.
//
// Round-5: stage ONE GROUP at a time (28 dw/sample instead of 84), per-wave,
// no barriers. LDS = 4 waves x 7168B = 28672B -> 5 blocks/CU -> 20 waves/CU.
// Per wave per group: 7 coalesced global_load_lds -> vmcnt(0) -> 7
// ds_read_b128 -> ~1500cy compute. 5 waves/SIMD hide the per-group stall.
__global__ __launch_bounds__(THREADS, 4) void olcnn_kernel(
    const float* __restrict__ x,
    const float* __restrict__ Wc, const float* __restrict__ bc,
    const float* __restrict__ Wh, const float* __restrict__ bh,
    const float* __restrict__ Wm, const float* __restrict__ bm,
    const float* __restrict__ Wo, const float* __restrict__ bo,
    float* __restrict__ out)
{
    __shared__ __align__(16) float sm[4 * WAVE_DW];   // 28672 B

    const int tid   = threadIdx.x;
    const int lane  = tid & 63;
    const int wid   = tid >> 6;
    const int samp  = blockIdx.x * THREADS + tid;     // this thread's sample
    const int TOTAL = (int)gridDim.x * THREADS * 81;  // dwords in x (42.5M)
    const int LIM   = TOTAL - 4;

    float* smw = sm + wid * WAVE_DW;                  // wave-private LDS slice
    // base dword of this wave's 64-sample run
    const int wbase81 = (blockIdx.x * THREADS + wid * 64) * 81;

    float res[4];

    #pragma unroll
    for (int G = 0; G < 3; ++G) {
        // WAR fence: previous group's ds_reads must retire before the DMA
        // overwrites the buffer. (G==0: trivially satisfied, ~free.)
        asm volatile("s_waitcnt lgkmcnt(0)" ::: "memory");
        __builtin_amdgcn_sched_barrier(0);

        // ---- stage group G for all 64 samples of this wave ----
        // chunk c = i*64 + lane; sample t = c/7, piece r = c%7 (7 x 16B/sample)
        // global src = (wbase+t)*81 + G*27 + 4r ; LDS dest = smw + c*16B
        {
            int t = (lane * 9363) >> 16;              // lane/7 (exact, lane<64)
            int r = lane - t * 7;
            int t81 = t * 81;
            const int gofs = wbase81 + G * 27;
            #pragma unroll
            for (int i = 0; i < 7; ++i) {
                int f0 = gofs + t81 + (r << 2);
                f0 = (f0 < LIM) ? f0 : LIM;           // clamp final chunk only
                __builtin_amdgcn_global_load_lds(
                    (gas_ptr)(x + f0), (las_ptr)(smw + i * 256), 16, 0, 0);
                // c += 64  (64 = 9*7+1): r+=1 wraps at 7 carrying into t
                t81 += (r == 6) ? 810 : 729;
                r = (r == 6) ? 0 : r + 1;
            }
        }
        asm volatile("s_waitcnt vmcnt(0)" ::: "memory");  // DMA -> LDS visible

        // ---- read own sample's 27 inputs (+1 slack) ----
        // start bank (lane*28)%32: 8-lane period covers all 32 banks 2x ->
        // the free 2-way pattern for ds_read_b128.
        float p[28];
        {
            const float4* rp = (const float4*)(smw + lane * GDW);
            #pragma unroll
            for (int q = 0; q < 7; ++q) {
                float4 v = rp[q];
                p[4*q+0] = v.x; p[4*q+1] = v.y; p[4*q+2] = v.z; p[4*q+3] = v.w;
            }
        }
        // Repair: the single clamped chunk (global-last sample, G=2) is
        // shifted down by one dword; re-read its tail directly (L3 hit).
        if (G == 2 && samp == (int)gridDim.x * THREADS - 1) {
            p[24] = x[TOTAL - 3]; p[25] = x[TOTAL - 2]; p[26] = x[TOTAL - 1];
        }

        // ---- compute group G (identical math to baseline) ----
        float hbuf[9];
        #pragma unroll
        for (int j = 0; j < 3; ++j) {              // conv patch g = (G, j)
            const int g = G * 3 + j;
            float feat[9];
            #pragma unroll
            for (int k = 0; k < 9; ++k) {          // 9 independent chains -> ILP
                float acc = bc[g * 9 + k];
                #pragma unroll
                for (int pr = 0; pr < 3; ++pr)
                    #pragma unroll
                    for (int pc = 0; pc < 3; ++pc)
                        acc = fmaf(p[pr * 9 + j * 3 + pc],
                                   Wc[(g * 9 + k) * 9 + pr * 3 + pc], acc);
                feat[k] = fast_sigmoid(acc);
            }
            #pragma unroll
            for (int n = 0; n < 3; ++n) {
                float acc = bh[g * 3 + n];
                #pragma unroll
                for (int pi = 0; pi < 9; ++pi)
                    acc = fmaf(feat[pi], Wh[(g * 3 + n) * 9 + pi], acc);
                hbuf[j * 3 + n] = fast_sigmoid(acc);
            }
        }

        float m[4];
        #pragma unroll
        for (int n = 0; n < 4; ++n) {
            float acc = bm[G * 4 + n];
            #pragma unroll
            for (int pi = 0; pi < 9; ++pi)
                acc = fmaf(hbuf[pi], Wm[(G * 4 + n) * 9 + pi], acc);
            m[n] = fast_sigmoid(acc);
        }

        // outputs reading middle group G (c % 3 == G): c = G, plus c = 3 @ G = 0
        {
            float acc = bo[G];
            #pragma unroll
            for (int pi = 0; pi < 4; ++pi)
                acc = fmaf(m[pi], Wo[G * 4 + pi], acc);
            res[G] = acc;
        }
        if (G == 0) {
            float acc = bo[3];
            #pragma unroll
            for (int pi = 0; pi < 4; ++pi)
                acc = fmaf(m[pi], Wo[3 * 4 + pi], acc);
            res[3] = acc;
        }
    }

    float4 o;
    o.x = res[0]; o.y = res[1]; o.z = res[2]; o.w = res[3];
    ((float4*)out)[samp] = o;                      // coalesced 16B/lane store
}

extern "C" void kernel_launch(void* const* d_in, const int* in_sizes, int n_in,
                              void* d_out, int out_size, void* d_ws, size_t ws_size,
                              hipStream_t stream) {
    const float* x  = (const float*)d_in[0];
    const float* Wc = (const float*)d_in[1];
    const float* bc = (const float*)d_in[2];
    const float* Wh = (const float*)d_in[3];
    const float* bh = (const float*)d_in[4];
    const float* Wm = (const float*)d_in[5];
    const float* bm = (const float*)d_in[6];
    const float* Wo = (const float*)d_in[7];
    const float* bo = (const float*)d_in[8];
    float* out = (float*)d_out;

    const int B = in_sizes[0] / 81;                // 524288
    const int blocks = B / THREADS;                // 2048
    olcnn_kernel<<<blocks, THREADS, 0, stream>>>(x, Wc, bc, Wh, bh, Wm, bm,
                                                 Wo, bo, out);
}